// Round 13
// baseline (152.538 us; speedup 1.0000x reference)
//
#include <hip/hip_runtime.h>
#include <hip/hip_bf16.h>

#define BATCH 32
#define CH 3
#define HH 256
#define WW 256
#define KS 29
#define PAD 14
#define NT_F 1000.0f

// blur band height: 16 rows -> 1536 blocks; with bounds(256,4) the reg cap is
// 128 (no spill at ~80 live) and occupancy = 4 blocks/CU. [R11 best config]
#define RB 16

typedef __attribute__((ext_vector_type(8))) short short8;
typedef __attribute__((ext_vector_type(4))) float f32x4;
typedef __attribute__((ext_vector_type(16))) float f32x16;

union U4 { short8 s8; uint4 u4; };

__device__ inline unsigned short bf16rne(float f) {
  unsigned u = __float_as_uint(f);
  unsigned r = (u + 0x7FFFu + ((u >> 16) & 1u)) >> 16;
  return (unsigned short)r;
}
__device__ inline unsigned pk_bf16(float a, float b) {
  union { __hip_bfloat162 h2; unsigned u; } cv;
  cv.h2 = __float22bfloat162_rn(make_float2(a, b));
  return cv.u;
}

// ws float layout:
//   (unused)  [1024]          @ 0
//   tcond [32][32]            @ 1024
//   w1n   ushort[3][32][16]   @ 2048
//   w2c   ushort[9][16][32]   @ 2816  (slot s holds och perm(s))
//   z     ushort[32][3][256][256] @ 5120  (bf16 blurred)
//   partial float[4096]       @ 3151872
//
// LESSONS LOG:
// R1: conv1-write bank fix correct but off critical path.
// R3: XCD swizzle cut convloss FETCH 58.5->18.5MB, dur unchanged.
// R5: private arrays need compile-time indexing (ring mod-6 -> scratch).
// R6: convloss occupancy theory falsified (+13% waves, dur worse).
// R7: barrier-removal neutral. Keep wave-private conv1 variant.
// R8: chunked no-spill blur ~43us (bounds(256,3), VGPR 80, WRITE==z).
// R9: fusion refuted (3.75x blur redundancy at 16x16 tiles -> 105us).
// R10: launch-bounds spill rule: bounds(256,6) caps VGPR at 64 -> scratch.
// R11: bounds(256,4)+RB16: blur <=43.5, total 134.06 (best). Wave-count
//     now measured at 3 and 4 waves/SIMD with ~flat response -> blur at a
//     per-block-latency floor; leave it. Ledger: fill 44.5 (untouchable) +
//     blur 42 + convloss 44 + reduce 3.
// R12: convloss 2-tile pipelined blocks (grid 4096 = 16 blocks/CU):
//     tile2's staging loads issued right after B1 -> ~900cy HBM latency
//     hides under tile1's conv; setup (weights/tc16/addressing) amortized
//     2x. zs4 double-buffered (+3.2KB, LDS 34.1KB -> 4 blocks/CU); hsw
//     reused same-wave (in-order LDS, no extra barrier). bounds(256,4)
//     keeps 128-reg cap (R10 rule).
//     [R12 bench = GPUAcquisitionTimeout (infra); resubmitted unchanged.]
//
// NOTE (r14): do NOT fold reduce into convloss via threadfence+atomic --
// device-scope fence across 8 non-coherent XCD L2s = 6x regression.

#define PARTIAL_OFF 3151872

// ---------------- blur (+ embedded weight-prep in last block) ----------------
__global__ __launch_bounds__(256, 4) void blur_kernel(
    const float* __restrict__ x, const int* __restrict__ t,
    const float* __restrict__ sched, const float* __restrict__ W1,
    const float* __restrict__ b1, const float* __restrict__ tw,
    const float* __restrict__ W2, float* __restrict__ ws,
    unsigned short* __restrict__ z) {
  int blk = blockIdx.x;
  int tid = threadIdx.x;

  if (blk >= BATCH * CH * RB) {
    // ---- weight-prep block (runs once; convloss launches after this kernel)
    float* tcond = ws + 1024;
    unsigned short* w1n = (unsigned short*)(ws + 2048);
    unsigned short* w2c = (unsigned short*)(ws + 2816);
    for (int i = tid; i < 1536; i += 256) {          // w1n [mf][och][slot]
      int mf = i >> 9, r = i & 511;
      int och = r >> 4, s = r & 15;
      int tp = mf * 4 + (s >> 2), ci = s & 3;
      w1n[i] = (ci < 3 && tp < 9) ? bf16rne(W1[och * 27 + ci * 9 + tp])
                                  : (unsigned short)0;
    }
    for (int i = tid; i < 4608; i += 256) {          // w2c [tap][oc][slot(perm)]
      int tap = i >> 9, r = i & 511;
      int n = r >> 5, s = r & 31;
      int och = (s & 3) + 8 * ((s >> 2) & 3) + 4 * (s >> 4);   // perm(s)
      int dy = tap / 3, dx = tap - dy * 3;
      w2c[i] = (n < 3) ? bf16rne(W2[((n * 32 + och) * 3 + dy) * 3 + dx])
                       : (unsigned short)0;
    }
    for (int i = tid; i < 1024; i += 256) {          // tcond
      int b = i >> 5, o = i & 31;
      tcond[i] = b1[o] + ((float)t[b] * (1.0f / NT_F)) * tw[o];
    }
    return;
  }

  // XCD-aware bijective swizzle (1536 = 8*192)
  {
    int wid = (blk & 7) * 192 + (blk >> 3);
    blk = wid;
  }

  __shared__ float vsp[RB][288];   // padded cols: idx = col + 16
  __shared__ float gkl[32];
  int rg = blk & (RB - 1);
  int bc = blk >> 4;               // log2(RB) = 4
  int b = bc / CH;
  int y0 = rg * RB;
  const float* xp = x + (size_t)bc * (HH * WW);

  // wave 0 computes this batch's gaussian kernel into LDS
  if (tid < 64) {
    float wexp = 0.0f;
    if (tid < KS) {
      float sigma = sched[t[b]];
      float xg = (float)(tid - PAD) / sigma;
      wexp = expf(-0.5f * xg * xg);
    }
    float s = wexp;
#pragma unroll
    for (int off = 32; off > 0; off >>= 1) s += __shfl_down(s, off);
    float tot = __shfl(s, 0);
    if (tid < 32) gkl[tid] = wexp / tot;
  }
  __syncthreads();

  // gaussian taps into registers once (wave-uniform broadcast reads)
  float gk[KS];
#pragma unroll
  for (int kk = 0; kk < KS; kk++) gk[kk] = gkl[kk];

  // ---- vertical pass, 2 chunks of 8 output rows (no-spill pattern) ----
#pragma unroll
  for (int ch = 0; ch < 2; ch++) {
    float acc[8];
#pragma unroll
    for (int yy = 0; yy < 8; yy++) acc[yy] = 0.0f;
#pragma unroll
    for (int i = 0; i < 36; i++) {         // input rows y0+8ch-14 .. +21
      int gy = y0 + 8 * ch - PAD + i;
      gy = (gy < 0) ? -gy : gy;
      gy = (gy >= HH) ? (2 * HH - 2 - gy) : gy;
      float v = xp[gy * WW + tid];
#pragma unroll
      for (int yy = 0; yy < 8; yy++) {
        int kk = i - yy;                   // compile-time per (i,yy)
        if (kk >= 0 && kk < KS) acc[yy] += gk[kk] * v;
      }
    }
#pragma unroll
    for (int yy = 0; yy < 8; yy++) vsp[8 * ch + yy][tid + 16] = acc[yy];
  }
  __syncthreads();
  {
    // 256 threads = 16 rows x 16 cols: single-pass horizontal mirror pads
    int row = tid >> 4, i2 = tid & 15;
    vsp[row][i2] = vsp[row][32 - i2];
    vsp[row][272 + i2] = vsp[row][270 - i2];
  }
  __syncthreads();

  size_t zb = (size_t)bc * (HH * WW);
#pragma unroll
  for (int it = 0; it < RB / 4; ++it) {   // 4 its: 1024 4-px units / 256 thr
    int unit = tid + 256 * it;
    int row = unit >> 6, cg = unit & 63;
    float w[36];
#pragma unroll
    for (int i = 0; i < 9; i++)
      *(float4*)&w[4 * i] = *(const float4*)&vsp[row][4 * (cg + i)];
    float o0 = 0, o1 = 0, o2 = 0, o3 = 0;
#pragma unroll
    for (int kk = 0; kk < KS; kk++) {
      float kv = gk[kk];
      o0 += kv * w[2 + kk];
      o1 += kv * w[3 + kk];
      o2 += kv * w[4 + kk];
      o3 += kv * w[5 + kk];
    }
    unsigned u0 = pk_bf16(o0, o1);
    unsigned u1 = pk_bf16(o2, o3);
    *(uint2*)&z[zb + (size_t)(y0 + row) * WW + 4 * cg] = make_uint2(u0, u1);
  }
}

// ---------------- fused conv1+ReLU+conv2+MSE, 2-tile pipelined ----------------
// grid (8,16,B); block 256 = 4 waves; TWO 16x16 output tiles per block
// (bx pair). Flow: stage t1 -> B1 -> [issue t2 staging loads] -> conv t1 ->
// [write t2 staging] -> B2 -> conv t2 -> reduce. hsw reused same-wave.
__global__ __launch_bounds__(256, 4) void convloss_kernel(
    const float* __restrict__ x, const float* __restrict__ ws,
    const float* __restrict__ b2g, float* __restrict__ partial) {
  __shared__ __align__(16) unsigned short zsA[400 * 4];      // tile1 staging
  __shared__ __align__(16) unsigned short zsB[400 * 4];      // tile2 staging
  __shared__ __align__(16) unsigned short hsw[4 * 6 * 18 * 32]; // per-wave strips
  __shared__ float wsum[4];

  const float* tcond = ws + 1024;
  const unsigned short* w1n = (const unsigned short*)(ws + 2048);
  const unsigned short* w2c = (const unsigned short*)(ws + 2816);
  const unsigned short* zg = (const unsigned short*)(ws + 5120);

  // XCD-aware bijective swizzle (4096 = 8*512)
  int flat = (blockIdx.z * 16 + blockIdx.y) * 8 + blockIdx.x;
  int wid = (flat & 7) * 512 + (flat >> 3);
  int b = wid >> 7;
  int by = (wid >> 3) & 15;
  int bxp = wid & 7;

  int tid = threadIdx.x;
  int x0a = bxp * 32, x0b = x0a + 16;
  int y0 = by * 16;
  const unsigned short* zbp = zg + (size_t)b * 3 * HH * WW;

  int lane = tid & 63;
  int q = lane >> 4;        // quad (16x16 shapes)
  int col = lane & 15;      // 16x16 m/n index
  int col32 = lane & 31;    // 32x32 n index (pixel)
  int h = lane >> 5;        // 32x32 half
  int wv = tid >> 6;        // wave id

  int colc = (col < 3) ? col : 0;
  float b2v = b2g[colc];
  const float* xb = x + (size_t)b * 3 * HH * WW;

  // staging geometry (tid<200): 2-px units
  int zy = tid / 10;
  int zx2 = tid - zy * 10;

  auto stage_load = [&](int x0t, unsigned& c0, unsigned& c1, unsigned& c2) {
    int gy = y0 - 2 + zy;
    int gx0 = x0t - 2 + 2 * zx2;
    bool ok = ((unsigned)gy < (unsigned)HH) && ((unsigned)gx0 < (unsigned)(WW - 1));
    int cy = (gy < 0) ? 0 : ((gy > 255) ? 255 : gy);
    int cx = (gx0 < 0) ? 0 : ((gx0 > 254) ? 254 : gx0);
    int gi = cy * WW + cx;
    c0 = *(const unsigned*)&zbp[gi];
    c1 = *(const unsigned*)&zbp[HH * WW + gi];
    c2 = *(const unsigned*)&zbp[2 * HH * WW + gi];
    unsigned m = ok ? 0xFFFFFFFFu : 0u;
    c0 &= m; c1 &= m; c2 &= m;
  };
  auto stage_write = [&](unsigned c0, unsigned c1, unsigned c2, unsigned short* zs) {
    uint4 o;
    o.x = (c0 & 0xFFFFu) | (c1 << 16);        // px0: ci0,ci1
    o.y = c2 & 0xFFFFu;                       // px0: ci2,pad
    o.z = (c0 >> 16) | (c1 & 0xFFFF0000u);    // px1: ci0,ci1
    o.w = c2 >> 16;                           // px1: ci2,pad
    *(uint4*)&zs[(zy * 20 + 2 * zx2) * 4] = o;
  };

  // ---- stage tile1 ----
  if (tid < 200) {
    unsigned c0, c1, c2;
    stage_load(x0a, c0, c1, c2);
    stage_write(c0, c1, c2, zsA);
  }

  // conv1 A fragments = weights [m=och][k=slot(h*8+j)]: b128 each
  U4 W0, W1f, W2f;
  W0.u4  = *(const uint4*)(w1n + 0 * 512 + col32 * 16 + h * 8);
  W1f.u4 = *(const uint4*)(w1n + 1 * 512 + col32 * 16 + h * 8);
  W2f.u4 = *(const uint4*)(w1n + 2 * 512 + col32 * 16 + h * 8);

  // conv1 C-init: tcond bias per (reg,h)
  f32x16 tc16;
#pragma unroll
  for (int r1 = 0; r1 < 4; r1++) {
    float4 v = *(const float4*)(tcond + b * 32 + 4 * h + 8 * r1);
    tc16[4 * r1 + 0] = v.x;
    tc16[4 * r1 + 1] = v.y;
    tc16[4 * r1 + 2] = v.z;
    tc16[4 * r1 + 3] = v.w;
  }

  // MSE x prefetch for tile1 (cold HBM; consumed at end of conv t1)
  float4 xpreA[4];
#pragma unroll
  for (int i = 0; i < 4; i++) {
    int g2 = wv * 4 + i;
    xpreA[i] = *(const float4*)&xb[colc * (HH * WW) + (y0 + g2) * WW + x0a + q * 4];
  }

  __syncthreads();   // B1: zsA staged

  // ---- issue tile2's staging loads NOW: ~900cy HBM latency hides under
  // conv t1 (~1500+cy). Values held in 3 regs until after conv t1.
  unsigned s0b = 0, s1b = 0, s2b = 0;
  if (tid < 200) stage_load(x0b, s0b, s1b, s2b);
  float4 xpreB[4];
#pragma unroll
  for (int i = 0; i < 4; i++) {
    int g2 = wv * 4 + i;
    xpreB[i] = *(const float4*)&xb[colc * (HH * WW) + (y0 + g2) * WW + x0b + q * 4];
  }

  // per-lane b64 read offsets (ushort units) for the 3 conv1 MFMAs' tap pairs
  int oA0 = h ? 8 : 0, oB0 = h ? 80 : 4;
  int oA1 = h ? 160 : 84, oB1 = h ? 164 : 88;
  const int oA2 = 168;
  char* hbw = (char*)hsw + wv * 6912;

  // ---- one full tile: conv1 (wave-private strip) -> conv2 -> MSE partial
  auto conv_tile = [&](const unsigned short* zs, const float4* xp) -> float {
#pragma unroll
    for (int g2 = 0; g2 < 4; g2++) {
      int e = g2 * 32 + col32;
      int ec = (e > 107) ? 107 : e;
      int row_l = ec / 18;              // 0..5
      int px = ec - row_l * 18;         // 0..17
      int ub = ((4 * wv + row_l) * 20 + px) * 4;
      uint2 l0 = *(const uint2*)&zs[ub + oA0];
      uint2 l1 = *(const uint2*)&zs[ub + oB0];
      uint2 l2 = *(const uint2*)&zs[ub + oA1];
      uint2 l3 = *(const uint2*)&zs[ub + oB1];
      uint2 l4 = *(const uint2*)&zs[ub + oA2];
      U4 Bz0, Bz1, Bz2;
      Bz0.u4 = make_uint4(l0.x, l0.y, l1.x, l1.y);
      Bz1.u4 = make_uint4(l2.x, l2.y, l3.x, l3.y);
      Bz2.u4 = make_uint4(l4.x, l4.y, 0u, 0u);
      f32x16 a = __builtin_amdgcn_mfma_f32_32x32x16_bf16(W0.s8, Bz0.s8, tc16, 0, 0, 0);
      a = __builtin_amdgcn_mfma_f32_32x32x16_bf16(W1f.s8, Bz1.s8, a, 0, 0, 0);
      a = __builtin_amdgcn_mfma_f32_32x32x16_bf16(W2f.s8, Bz2.s8, a, 0, 0, 0);
      if (e < 108) {
        unsigned wpk[8];
#pragma unroll
        for (int m = 0; m < 8; m++)
          wpk[m] = pk_bf16(fmaxf(a[2 * m], 0.0f), fmaxf(a[2 * m + 1], 0.0f));
        int wb = row_l * 1152 + px * 64 + ((32 * h) ^ ((px & 2) << 4));
        *(uint4*)(hbw + wb)      = make_uint4(wpk[0], wpk[1], wpk[2], wpk[3]);
        *(uint4*)(hbw + wb + 16) = make_uint4(wpk[4], wpk[5], wpk[6], wpk[7]);
      }
    }
    // NO barrier: conv2 reads only this wave's strip (same-wave, in-order LDS)

    // conv2 B-frags loaded per tile (L2-hot; keeps conv1 reg pressure low)
    U4 Bt[3][3];
    {
      const unsigned short* wbase = w2c + col * 32 + q * 8;
#pragma unroll
      for (int dy = 0; dy < 3; dy++)
#pragma unroll
        for (int dx = 0; dx < 3; dx++)
          Bt[dy][dx].u4 = *(const uint4*)(wbase + (dy * 3 + dx) * 512);
    }

    const f32x4 bcv = {b2v, b2v, b2v, b2v};
    f32x4 dacc[4];
#pragma unroll
    for (int i = 0; i < 4; i++) dacc[i] = bcv;
#pragma unroll
    for (int dx = 0; dx < 3; dx++) {
      int px = col + dx;                         // 0..17
      const char* bp = (const char*)hbw + px * 64 + ((q * 16) ^ ((px & 2) << 4));
#pragma unroll
      for (int rr = 0; rr < 6; rr++) {
        U4 A;
        A.u4 = *(const uint4*)(bp + rr * 1152);  // one b128, imm offset
        if (rr < 4)
          dacc[rr] = __builtin_amdgcn_mfma_f32_16x16x32_bf16(A.s8, Bt[0][dx].s8, dacc[rr], 0, 0, 0);
        if (rr >= 1 && rr < 5)
          dacc[rr - 1] = __builtin_amdgcn_mfma_f32_16x16x32_bf16(A.s8, Bt[1][dx].s8, dacc[rr - 1], 0, 0, 0);
        if (rr >= 2)
          dacc[rr - 2] = __builtin_amdgcn_mfma_f32_16x16x32_bf16(A.s8, Bt[2][dx].s8, dacc[rr - 2], 0, 0, 0);
      }
    }

    float s = 0.0f;
    if (col < 3) {
#pragma unroll
      for (int i = 0; i < 4; i++) {
        float4 xv = xp[i];
        float d0 = xv.x - dacc[i][0];
        float d1 = xv.y - dacc[i][1];
        float d2 = xv.z - dacc[i][2];
        float d3 = xv.w - dacc[i][3];
        s += d0 * d0 + d1 * d1 + d2 * d2 + d3 * d3;
      }
    }
    return s;
  };

  // ---- tile1 compute (t2 staging loads in flight underneath) ----
  float sacc = conv_tile(zsA, xpreA);

  // ---- write tile2 staging (vmcnt wait was hidden under conv t1) ----
  if (tid < 200) stage_write(s0b, s1b, s2b, zsB);
  __syncthreads();   // B2: zsB staged; hsw t1 reads done (same-wave order)

  // ---- tile2 compute ----
  sacc += conv_tile(zsB, xpreB);

  // ---- block reduce ----
#pragma unroll
  for (int off = 32; off > 0; off >>= 1) sacc += __shfl_down(sacc, off);
  if (lane == 0) wsum[wv] = sacc;
  __syncthreads();   // B3
  if (tid == 0) {
    int bid = (b * 16 + by) * 8 + bxp;
    partial[bid] = wsum[0] + wsum[1] + wsum[2] + wsum[3];
  }
}

// ---------------- final reduce: 4096 partials -> out[0] ----------------
__global__ __launch_bounds__(256) void reduce_kernel(const float* __restrict__ partial,
                                                     float* __restrict__ out) {
  __shared__ float wsum[4];
  int tid = threadIdx.x;
  float s = 0.0f;
#pragma unroll
  for (int i = 0; i < 4; i++) {
    float4 v = *(const float4*)&partial[(tid + 256 * i) * 4];
    s += v.x + v.y + v.z + v.w;
  }
#pragma unroll
  for (int off = 32; off > 0; off >>= 1) s += __shfl_down(s, off);
  if ((tid & 63) == 0) wsum[tid >> 6] = s;
  __syncthreads();
  if (tid == 0)
    out[0] = (wsum[0] + wsum[1] + wsum[2] + wsum[3]) * (1.0f / 6291456.0f);
}

extern "C" void kernel_launch(void* const* d_in, const int* in_sizes, int n_in,
                              void* d_out, int out_size, void* d_ws, size_t ws_size,
                              hipStream_t stream) {
  const float* x = (const float*)d_in[0];
  const int* t = (const int*)d_in[1];
  const float* W1 = (const float*)d_in[2];
  const float* b1 = (const float*)d_in[3];
  const float* tw = (const float*)d_in[4];
  const float* W2 = (const float*)d_in[5];
  const float* b2 = (const float*)d_in[6];
  const float* sched = (const float*)d_in[7];
  float* out = (float*)d_out;
  float* ws = (float*)d_ws;
  unsigned short* z = (unsigned short*)(ws + 5120);
  float* partial = ws + PARTIAL_OFF;

  blur_kernel<<<BATCH * CH * RB + 1, 256, 0, stream>>>(x, t, sched, W1, b1, tw, W2, ws, z);
  dim3 grid(8, 16, BATCH);
  convloss_kernel<<<grid, 256, 0, stream>>>(x, ws, b2, partial);
  reduce_kernel<<<1, 256, 0, stream>>>(partial, out);
}

// Round 15
// 146.061 us; speedup vs baseline: 1.0443x; 1.0443x over previous
//
#include <hip/hip_runtime.h>
#include <hip/hip_bf16.h>

#define BATCH 32
#define CH 3
#define HH 256
#define WW 256
#define KS 29
#define PAD 14
#define NT_F 1000.0f

// blur band height: 16 rows -> 1536 blocks; bounds(256,4) = 128-reg cap,
// no spill at ~80 live, 4 blocks/CU. [R11 best config]
#define RB 16

typedef __attribute__((ext_vector_type(8))) short short8;
typedef __attribute__((ext_vector_type(4))) float f32x4;
typedef __attribute__((ext_vector_type(16))) float f32x16;

union U4 { short8 s8; uint4 u4; };

__device__ inline unsigned short bf16rne(float f) {
  unsigned u = __float_as_uint(f);
  unsigned r = (u + 0x7FFFu + ((u >> 16) & 1u)) >> 16;
  return (unsigned short)r;
}
__device__ inline unsigned pk_bf16(float a, float b) {
  union { __hip_bfloat162 h2; unsigned u; } cv;
  cv.h2 = __float22bfloat162_rn(make_float2(a, b));
  return cv.u;
}

// ws float layout:
//   (unused)  [1024]          @ 0
//   tcond [32][32]            @ 1024
//   w1n   ushort[3][32][16]   @ 2048
//   w2c   ushort[9][16][32]   @ 2816  (slot s holds och perm(s))
//   z     ushort[32][3][256][256] @ 5120  (bf16 blurred)
//   partial float[4096]       @ 3151872
//
// LESSONS LOG:
// R1: conv1-write bank fix correct but off critical path.
// R3: XCD swizzle cut convloss FETCH 58.5->18.5MB, dur unchanged.
// R5: private arrays need compile-time indexing (ring mod-6 -> scratch).
// R6: convloss occupancy theory falsified (+13% waves, dur worse).
// R7: barrier-removal neutral. Keep wave-private conv1 variant.
// R8: chunked no-spill blur ~43us. R9: fusion refuted (3.75x redundancy).
// R10: launch-bounds spill rule: bounds(256,6) caps VGPR at 64 -> scratch.
// R11: bounds(256,4)+RB16: total 134.06 (best). blur at per-block floor.
// R13: 2-tile pipeline REGRESSED (59.7us, WRITE 86MB): rule #20 via lambda
//     POINTER-ARG — conv_tile(const float4* xp) forced xpreA/B into scratch.
//     Theory untested; implementation bug. Fix: pass MSE values BY VALUE
//     (4x float4 scalars), move xpreB load after B2 (barrier vmcnt-drain
//     means pre-B2 loads are exposed AT B2; post-B2 loads are covered by
//     tile2's ~1500cy conv, same pattern R7 proved). Peak live ~109 < 128.
//     [R14 bench = GPUAcquisitionTimeout (infra); resubmitted unchanged.]
//
// NOTE (r14): do NOT fold reduce into convloss via threadfence+atomic --
// device-scope fence across 8 non-coherent XCD L2s = 6x regression.

#define PARTIAL_OFF 3151872

// ---------------- blur (+ embedded weight-prep in last block) ----------------
__global__ __launch_bounds__(256, 4) void blur_kernel(
    const float* __restrict__ x, const int* __restrict__ t,
    const float* __restrict__ sched, const float* __restrict__ W1,
    const float* __restrict__ b1, const float* __restrict__ tw,
    const float* __restrict__ W2, float* __restrict__ ws,
    unsigned short* __restrict__ z) {
  int blk = blockIdx.x;
  int tid = threadIdx.x;

  if (blk >= BATCH * CH * RB) {
    // ---- weight-prep block (runs once; convloss launches after this kernel)
    float* tcond = ws + 1024;
    unsigned short* w1n = (unsigned short*)(ws + 2048);
    unsigned short* w2c = (unsigned short*)(ws + 2816);
    for (int i = tid; i < 1536; i += 256) {          // w1n [mf][och][slot]
      int mf = i >> 9, r = i & 511;
      int och = r >> 4, s = r & 15;
      int tp = mf * 4 + (s >> 2), ci = s & 3;
      w1n[i] = (ci < 3 && tp < 9) ? bf16rne(W1[och * 27 + ci * 9 + tp])
                                  : (unsigned short)0;
    }
    for (int i = tid; i < 4608; i += 256) {          // w2c [tap][oc][slot(perm)]
      int tap = i >> 9, r = i & 511;
      int n = r >> 5, s = r & 31;
      int och = (s & 3) + 8 * ((s >> 2) & 3) + 4 * (s >> 4);   // perm(s)
      int dy = tap / 3, dx = tap - dy * 3;
      w2c[i] = (n < 3) ? bf16rne(W2[((n * 32 + och) * 3 + dy) * 3 + dx])
                       : (unsigned short)0;
    }
    for (int i = tid; i < 1024; i += 256) {          // tcond
      int b = i >> 5, o = i & 31;
      tcond[i] = b1[o] + ((float)t[b] * (1.0f / NT_F)) * tw[o];
    }
    return;
  }

  // XCD-aware bijective swizzle (1536 = 8*192)
  {
    int wid = (blk & 7) * 192 + (blk >> 3);
    blk = wid;
  }

  __shared__ float vsp[RB][288];   // padded cols: idx = col + 16
  __shared__ float gkl[32];
  int rg = blk & (RB - 1);
  int bc = blk >> 4;               // log2(RB) = 4
  int b = bc / CH;
  int y0 = rg * RB;
  const float* xp = x + (size_t)bc * (HH * WW);

  // wave 0 computes this batch's gaussian kernel into LDS
  if (tid < 64) {
    float wexp = 0.0f;
    if (tid < KS) {
      float sigma = sched[t[b]];
      float xg = (float)(tid - PAD) / sigma;
      wexp = expf(-0.5f * xg * xg);
    }
    float s = wexp;
#pragma unroll
    for (int off = 32; off > 0; off >>= 1) s += __shfl_down(s, off);
    float tot = __shfl(s, 0);
    if (tid < 32) gkl[tid] = wexp / tot;
  }
  __syncthreads();

  // gaussian taps into registers once (wave-uniform broadcast reads)
  float gk[KS];
#pragma unroll
  for (int kk = 0; kk < KS; kk++) gk[kk] = gkl[kk];

  // ---- vertical pass, 2 chunks of 8 output rows (no-spill pattern) ----
#pragma unroll
  for (int ch = 0; ch < 2; ch++) {
    float acc[8];
#pragma unroll
    for (int yy = 0; yy < 8; yy++) acc[yy] = 0.0f;
#pragma unroll
    for (int i = 0; i < 36; i++) {         // input rows y0+8ch-14 .. +21
      int gy = y0 + 8 * ch - PAD + i;
      gy = (gy < 0) ? -gy : gy;
      gy = (gy >= HH) ? (2 * HH - 2 - gy) : gy;
      float v = xp[gy * WW + tid];
#pragma unroll
      for (int yy = 0; yy < 8; yy++) {
        int kk = i - yy;                   // compile-time per (i,yy)
        if (kk >= 0 && kk < KS) acc[yy] += gk[kk] * v;
      }
    }
#pragma unroll
    for (int yy = 0; yy < 8; yy++) vsp[8 * ch + yy][tid + 16] = acc[yy];
  }
  __syncthreads();
  {
    // 256 threads = 16 rows x 16 cols: single-pass horizontal mirror pads
    int row = tid >> 4, i2 = tid & 15;
    vsp[row][i2] = vsp[row][32 - i2];
    vsp[row][272 + i2] = vsp[row][270 - i2];
  }
  __syncthreads();

  size_t zb = (size_t)bc * (HH * WW);
#pragma unroll
  for (int it = 0; it < RB / 4; ++it) {   // 4 its: 1024 4-px units / 256 thr
    int unit = tid + 256 * it;
    int row = unit >> 6, cg = unit & 63;
    float w[36];
#pragma unroll
    for (int i = 0; i < 9; i++)
      *(float4*)&w[4 * i] = *(const float4*)&vsp[row][4 * (cg + i)];
    float o0 = 0, o1 = 0, o2 = 0, o3 = 0;
#pragma unroll
    for (int kk = 0; kk < KS; kk++) {
      float kv = gk[kk];
      o0 += kv * w[2 + kk];
      o1 += kv * w[3 + kk];
      o2 += kv * w[4 + kk];
      o3 += kv * w[5 + kk];
    }
    unsigned u0 = pk_bf16(o0, o1);
    unsigned u1 = pk_bf16(o2, o3);
    *(uint2*)&z[zb + (size_t)(y0 + row) * WW + 4 * cg] = make_uint2(u0, u1);
  }
}

// ---------------- fused conv1+ReLU+conv2+MSE, 2-tile pipelined ----------------
// grid (8,16,B); block 256 = 4 waves; TWO 16x16 output tiles per block.
// Flow: stage t1 -> B1 -> [issue t2 z-staging loads] -> conv t1 (covers them)
// -> write t2 staging -> B2 -> [issue t2 MSE x loads] -> conv t2 (covers
// them; no barrier until B3) -> reduce. hsw reused same-wave. MSE values
// passed BY VALUE into conv_tile (no pointer-indexed local arrays, rule #20).
__global__ __launch_bounds__(256, 4) void convloss_kernel(
    const float* __restrict__ x, const float* __restrict__ ws,
    const float* __restrict__ b2g, float* __restrict__ partial) {
  __shared__ __align__(16) unsigned short zsA[400 * 4];      // tile1 staging
  __shared__ __align__(16) unsigned short zsB[400 * 4];      // tile2 staging
  __shared__ __align__(16) unsigned short hsw[4 * 6 * 18 * 32]; // per-wave strips
  __shared__ float wsum[4];

  const float* tcond = ws + 1024;
  const unsigned short* w1n = (const unsigned short*)(ws + 2048);
  const unsigned short* w2c = (const unsigned short*)(ws + 2816);
  const unsigned short* zg = (const unsigned short*)(ws + 5120);

  // XCD-aware bijective swizzle (4096 = 8*512)
  int flat = (blockIdx.z * 16 + blockIdx.y) * 8 + blockIdx.x;
  int wid = (flat & 7) * 512 + (flat >> 3);
  int b = wid >> 7;
  int by = (wid >> 3) & 15;
  int bxp = wid & 7;

  int tid = threadIdx.x;
  int x0a = bxp * 32, x0b = x0a + 16;
  int y0 = by * 16;
  const unsigned short* zbp = zg + (size_t)b * 3 * HH * WW;

  int lane = tid & 63;
  int q = lane >> 4;        // quad (16x16 shapes)
  int col = lane & 15;      // 16x16 m/n index
  int col32 = lane & 31;    // 32x32 n index (pixel)
  int h = lane >> 5;        // 32x32 half
  int wv = tid >> 6;        // wave id

  int colc = (col < 3) ? col : 0;
  float b2v = b2g[colc];
  const float* xb = x + (size_t)b * 3 * HH * WW;
  const float* xrow = xb + colc * (HH * WW) + (y0 + wv * 4) * WW + q * 4;

  // staging geometry (tid<200): 2-px units
  int zy = tid / 10;
  int zx2 = tid - zy * 10;

  auto stage_load = [&](int x0t, unsigned& c0, unsigned& c1, unsigned& c2) {
    int gy = y0 - 2 + zy;
    int gx0 = x0t - 2 + 2 * zx2;
    bool ok = ((unsigned)gy < (unsigned)HH) && ((unsigned)gx0 < (unsigned)(WW - 1));
    int cy = (gy < 0) ? 0 : ((gy > 255) ? 255 : gy);
    int cx = (gx0 < 0) ? 0 : ((gx0 > 254) ? 254 : gx0);
    int gi = cy * WW + cx;
    c0 = *(const unsigned*)&zbp[gi];
    c1 = *(const unsigned*)&zbp[HH * WW + gi];
    c2 = *(const unsigned*)&zbp[2 * HH * WW + gi];
    unsigned m = ok ? 0xFFFFFFFFu : 0u;
    c0 &= m; c1 &= m; c2 &= m;
  };
  auto stage_write = [&](unsigned c0, unsigned c1, unsigned c2, unsigned short* zs) {
    uint4 o;
    o.x = (c0 & 0xFFFFu) | (c1 << 16);        // px0: ci0,ci1
    o.y = c2 & 0xFFFFu;                       // px0: ci2,pad
    o.z = (c0 >> 16) | (c1 & 0xFFFF0000u);    // px1: ci0,ci1
    o.w = c2 >> 16;                           // px1: ci2,pad
    *(uint4*)&zs[(zy * 20 + 2 * zx2) * 4] = o;
  };

  // ---- stage tile1 ----
  if (tid < 200) {
    unsigned c0, c1, c2;
    stage_load(x0a, c0, c1, c2);
    stage_write(c0, c1, c2, zsA);
  }

  // conv1 A fragments = weights [m=och][k=slot(h*8+j)]: b128 each
  U4 W0, W1f, W2f;
  W0.u4  = *(const uint4*)(w1n + 0 * 512 + col32 * 16 + h * 8);
  W1f.u4 = *(const uint4*)(w1n + 1 * 512 + col32 * 16 + h * 8);
  W2f.u4 = *(const uint4*)(w1n + 2 * 512 + col32 * 16 + h * 8);

  // conv1 C-init: tcond bias per (reg,h)
  f32x16 tc16;
#pragma unroll
  for (int r1 = 0; r1 < 4; r1++) {
    float4 v = *(const float4*)(tcond + b * 32 + 4 * h + 8 * r1);
    tc16[4 * r1 + 0] = v.x;
    tc16[4 * r1 + 1] = v.y;
    tc16[4 * r1 + 2] = v.z;
    tc16[4 * r1 + 3] = v.w;
  }

  // MSE x values for tile1 (cold HBM; consumed at end of conv t1) — SCALARS
  float4 xa0 = *(const float4*)&xrow[x0a];
  float4 xa1 = *(const float4*)&xrow[x0a + WW];
  float4 xa2 = *(const float4*)&xrow[x0a + 2 * WW];
  float4 xa3 = *(const float4*)&xrow[x0a + 3 * WW];

  __syncthreads();   // B1: zsA staged

  // ---- issue tile2's z-staging loads NOW: ~900cy HBM/L2 latency hides
  // under conv t1 (~1500+cy); consumed at stage_write before B2.
  unsigned s0b = 0, s1b = 0, s2b = 0;
  if (tid < 200) stage_load(x0b, s0b, s1b, s2b);

  // per-lane b64 read offsets (ushort units) for the 3 conv1 MFMAs' tap pairs
  int oA0 = h ? 8 : 0, oB0 = h ? 80 : 4;
  int oA1 = h ? 160 : 84, oB1 = h ? 164 : 88;
  const int oA2 = 168;
  char* hbw = (char*)hsw + wv * 6912;

  // ---- one full tile; MSE x comes in BY VALUE (stays in VGPRs) ----
  auto conv_tile = [&](const unsigned short* zs, float4 xv0, float4 xv1,
                       float4 xv2, float4 xv3) -> float {
#pragma unroll
    for (int g2 = 0; g2 < 4; g2++) {
      int e = g2 * 32 + col32;
      int ec = (e > 107) ? 107 : e;
      int row_l = ec / 18;              // 0..5
      int px = ec - row_l * 18;         // 0..17
      int ub = ((4 * wv + row_l) * 20 + px) * 4;
      uint2 l0 = *(const uint2*)&zs[ub + oA0];
      uint2 l1 = *(const uint2*)&zs[ub + oB0];
      uint2 l2 = *(const uint2*)&zs[ub + oA1];
      uint2 l3 = *(const uint2*)&zs[ub + oB1];
      uint2 l4 = *(const uint2*)&zs[ub + oA2];
      U4 Bz0, Bz1, Bz2;
      Bz0.u4 = make_uint4(l0.x, l0.y, l1.x, l1.y);
      Bz1.u4 = make_uint4(l2.x, l2.y, l3.x, l3.y);
      Bz2.u4 = make_uint4(l4.x, l4.y, 0u, 0u);
      f32x16 a = __builtin_amdgcn_mfma_f32_32x32x16_bf16(W0.s8, Bz0.s8, tc16, 0, 0, 0);
      a = __builtin_amdgcn_mfma_f32_32x32x16_bf16(W1f.s8, Bz1.s8, a, 0, 0, 0);
      a = __builtin_amdgcn_mfma_f32_32x32x16_bf16(W2f.s8, Bz2.s8, a, 0, 0, 0);
      if (e < 108) {
        unsigned wpk[8];
#pragma unroll
        for (int m = 0; m < 8; m++)
          wpk[m] = pk_bf16(fmaxf(a[2 * m], 0.0f), fmaxf(a[2 * m + 1], 0.0f));
        int wb = row_l * 1152 + px * 64 + ((32 * h) ^ ((px & 2) << 4));
        *(uint4*)(hbw + wb)      = make_uint4(wpk[0], wpk[1], wpk[2], wpk[3]);
        *(uint4*)(hbw + wb + 16) = make_uint4(wpk[4], wpk[5], wpk[6], wpk[7]);
      }
    }
    // NO barrier: conv2 reads only this wave's strip (same-wave, in-order LDS)

    // conv2 B-frags loaded per tile (L2-hot; keeps conv1 reg pressure low)
    U4 Bt[3][3];
    {
      const unsigned short* wbase = w2c + col * 32 + q * 8;
#pragma unroll
      for (int dy = 0; dy < 3; dy++)
#pragma unroll
        for (int dx = 0; dx < 3; dx++)
          Bt[dy][dx].u4 = *(const uint4*)(wbase + (dy * 3 + dx) * 512);
    }

    const f32x4 bcv = {b2v, b2v, b2v, b2v};
    f32x4 dacc[4];
#pragma unroll
    for (int i = 0; i < 4; i++) dacc[i] = bcv;
#pragma unroll
    for (int dx = 0; dx < 3; dx++) {
      int px = col + dx;                         // 0..17
      const char* bp = (const char*)hbw + px * 64 + ((q * 16) ^ ((px & 2) << 4));
#pragma unroll
      for (int rr = 0; rr < 6; rr++) {
        U4 A;
        A.u4 = *(const uint4*)(bp + rr * 1152);  // one b128, imm offset
        if (rr < 4)
          dacc[rr] = __builtin_amdgcn_mfma_f32_16x16x32_bf16(A.s8, Bt[0][dx].s8, dacc[rr], 0, 0, 0);
        if (rr >= 1 && rr < 5)
          dacc[rr - 1] = __builtin_amdgcn_mfma_f32_16x16x32_bf16(A.s8, Bt[1][dx].s8, dacc[rr - 1], 0, 0, 0);
        if (rr >= 2)
          dacc[rr - 2] = __builtin_amdgcn_mfma_f32_16x16x32_bf16(A.s8, Bt[2][dx].s8, dacc[rr - 2], 0, 0, 0);
      }
    }

    float s = 0.0f;
    if (col < 3) {
      float d;
      d = xv0.x - dacc[0][0]; s += d * d;
      d = xv0.y - dacc[0][1]; s += d * d;
      d = xv0.z - dacc[0][2]; s += d * d;
      d = xv0.w - dacc[0][3]; s += d * d;
      d = xv1.x - dacc[1][0]; s += d * d;
      d = xv1.y - dacc[1][1]; s += d * d;
      d = xv1.z - dacc[1][2]; s += d * d;
      d = xv1.w - dacc[1][3]; s += d * d;
      d = xv2.x - dacc[2][0]; s += d * d;
      d = xv2.y - dacc[2][1]; s += d * d;
      d = xv2.z - dacc[2][2]; s += d * d;
      d = xv2.w - dacc[2][3]; s += d * d;
      d = xv3.x - dacc[3][0]; s += d * d;
      d = xv3.y - dacc[3][1]; s += d * d;
      d = xv3.z - dacc[3][2]; s += d * d;
      d = xv3.w - dacc[3][3]; s += d * d;
    }
    return s;
  };

  // ---- tile1 compute (t2 z-staging loads in flight underneath) ----
  float sacc = conv_tile(zsA, xa0, xa1, xa2, xa3);

  // ---- write tile2 staging (vmcnt wait was hidden under conv t1) ----
  if (tid < 200) stage_write(s0b, s1b, s2b, zsB);
  __syncthreads();   // B2: zsB staged; hsw t1 reads done (same-wave order)

  // ---- issue tile2 MSE x loads AFTER B2: covered by conv t2 (~1500cy),
  // no intervening barrier before their consumption.
  float4 xb0 = *(const float4*)&xrow[x0b];
  float4 xb1 = *(const float4*)&xrow[x0b + WW];
  float4 xb2 = *(const float4*)&xrow[x0b + 2 * WW];
  float4 xb3 = *(const float4*)&xrow[x0b + 3 * WW];

  // ---- tile2 compute ----
  sacc += conv_tile(zsB, xb0, xb1, xb2, xb3);

  // ---- block reduce ----
#pragma unroll
  for (int off = 32; off > 0; off >>= 1) sacc += __shfl_down(sacc, off);
  if (lane == 0) wsum[wv] = sacc;
  __syncthreads();   // B3
  if (tid == 0) {
    int bid = (b * 16 + by) * 8 + bxp;
    partial[bid] = wsum[0] + wsum[1] + wsum[2] + wsum[3];
  }
}

// ---------------- final reduce: 4096 partials -> out[0] ----------------
__global__ __launch_bounds__(256) void reduce_kernel(const float* __restrict__ partial,
                                                     float* __restrict__ out) {
  __shared__ float wsum[4];
  int tid = threadIdx.x;
  float s = 0.0f;
#pragma unroll
  for (int i = 0; i < 4; i++) {
    float4 v = *(const float4*)&partial[(tid + 256 * i) * 4];
    s += v.x + v.y + v.z + v.w;
  }
#pragma unroll
  for (int off = 32; off > 0; off >>= 1) s += __shfl_down(s, off);
  if ((tid & 63) == 0) wsum[tid >> 6] = s;
  __syncthreads();
  if (tid == 0)
    out[0] = (wsum[0] + wsum[1] + wsum[2] + wsum[3]) * (1.0f / 6291456.0f);
}

extern "C" void kernel_launch(void* const* d_in, const int* in_sizes, int n_in,
                              void* d_out, int out_size, void* d_ws, size_t ws_size,
                              hipStream_t stream) {
  const float* x = (const float*)d_in[0];
  const int* t = (const int*)d_in[1];
  const float* W1 = (const float*)d_in[2];
  const float* b1 = (const float*)d_in[3];
  const float* tw = (const float*)d_in[4];
  const float* W2 = (const float*)d_in[5];
  const float* b2 = (const float*)d_in[6];
  const float* sched = (const float*)d_in[7];
  float* out = (float*)d_out;
  float* ws = (float*)d_ws;
  unsigned short* z = (unsigned short*)(ws + 5120);
  float* partial = ws + PARTIAL_OFF;

  blur_kernel<<<BATCH * CH * RB + 1, 256, 0, stream>>>(x, t, sched, W1, b1, tw, W2, ws, z);
  dim3 grid(8, 16, BATCH);
  convloss_kernel<<<grid, 256, 0, stream>>>(x, ws, b2, partial);
  reduce_kernel<<<1, 256, 0, stream>>>(partial, out);
}

// Round 16
// 142.747 us; speedup vs baseline: 1.0686x; 1.0232x over previous
//
#include <hip/hip_runtime.h>
#include <hip/hip_bf16.h>

#define BATCH 32
#define CH 3
#define HH 256
#define WW 256
#define KS 29
#define PAD 14
#define NT_F 1000.0f

// blur band height: 16 rows -> 1536 blocks; bounds(256,4), VGPR 80, no spill,
// 4 blocks/CU. [R11 best config]
#define RB 16

typedef __attribute__((ext_vector_type(8))) short short8;
typedef __attribute__((ext_vector_type(4))) float f32x4;
typedef __attribute__((ext_vector_type(16))) float f32x16;

union U4 { short8 s8; uint4 u4; };

__device__ inline unsigned short bf16rne(float f) {
  unsigned u = __float_as_uint(f);
  unsigned r = (u + 0x7FFFu + ((u >> 16) & 1u)) >> 16;
  return (unsigned short)r;
}
__device__ inline unsigned pk_bf16(float a, float b) {
  union { __hip_bfloat162 h2; unsigned u; } cv;
  cv.h2 = __float22bfloat162_rn(make_float2(a, b));
  return cv.u;
}

// ws float layout:
//   (unused)  [1024]          @ 0
//   tcond [32][32]            @ 1024
//   w1n   ushort[3][32][16]   @ 2048
//   w2c   ushort[9][16][32]   @ 2816  (slot s holds och perm(s))
//   z     ushort[32][3][256][256] @ 5120  (bf16 blurred)
//   partial float[4096]       @ 3151872
//
// LESSONS LOG:
// R1: conv1-write bank fix correct but off critical path.
// R3: XCD swizzle cut convloss FETCH 58.5->18.5MB, dur unchanged.
// R5: private arrays need compile-time indexing (ring mod-6 -> scratch).
// R6: convloss occupancy theory falsified (+13% waves, dur worse).
// R7: barrier-removal neutral. Keep wave-private conv1 variant.
// R8: chunked no-spill blur ~43us. R9: fusion refuted (3.75x redundancy).
// R10: launch-bounds spill rule: declared waves cap VGPR (pool ~512/SIMD).
// R11: bounds(256,4)+RB16: total 134.06 (best). blur at per-block floor.
// R13: 2-tile pipeline: lambda pointer-arg -> 86MB scratch (rule #20).
// R15: by-value fix halved scratch (25MB) but VGPR=64 < ~100 live: the
//     ALLOCATOR chose the 8-waves/SIMD band (64 regs) and spilled, despite
//     (256,4) permitting 128. R11's identical conv_tile registerizes at 44;
//     blur under (256,4) got 80 -> heuristic, not necessity.
// R16 (this): __launch_bounds__(256, 2) on convloss — LDS (34.3KB) already
//     caps occupancy at 4 blocks/CU, so lowering the declared wave target
//     frees the allocator to ~128 regs at ZERO occupancy cost. Final try of
//     the 2-tile pipeline; if spills persist or dur>=44 -> revert to R11.
//
// NOTE (r14): do NOT fold reduce into convloss via threadfence+atomic --
// device-scope fence across 8 non-coherent XCD L2s = 6x regression.

#define PARTIAL_OFF 3151872

// ---------------- blur (+ embedded weight-prep in last block) ----------------
__global__ __launch_bounds__(256, 4) void blur_kernel(
    const float* __restrict__ x, const int* __restrict__ t,
    const float* __restrict__ sched, const float* __restrict__ W1,
    const float* __restrict__ b1, const float* __restrict__ tw,
    const float* __restrict__ W2, float* __restrict__ ws,
    unsigned short* __restrict__ z) {
  int blk = blockIdx.x;
  int tid = threadIdx.x;

  if (blk >= BATCH * CH * RB) {
    // ---- weight-prep block (runs once; convloss launches after this kernel)
    float* tcond = ws + 1024;
    unsigned short* w1n = (unsigned short*)(ws + 2048);
    unsigned short* w2c = (unsigned short*)(ws + 2816);
    for (int i = tid; i < 1536; i += 256) {          // w1n [mf][och][slot]
      int mf = i >> 9, r = i & 511;
      int och = r >> 4, s = r & 15;
      int tp = mf * 4 + (s >> 2), ci = s & 3;
      w1n[i] = (ci < 3 && tp < 9) ? bf16rne(W1[och * 27 + ci * 9 + tp])
                                  : (unsigned short)0;
    }
    for (int i = tid; i < 4608; i += 256) {          // w2c [tap][oc][slot(perm)]
      int tap = i >> 9, r = i & 511;
      int n = r >> 5, s = r & 31;
      int och = (s & 3) + 8 * ((s >> 2) & 3) + 4 * (s >> 4);   // perm(s)
      int dy = tap / 3, dx = tap - dy * 3;
      w2c[i] = (n < 3) ? bf16rne(W2[((n * 32 + och) * 3 + dy) * 3 + dx])
                       : (unsigned short)0;
    }
    for (int i = tid; i < 1024; i += 256) {          // tcond
      int b = i >> 5, o = i & 31;
      tcond[i] = b1[o] + ((float)t[b] * (1.0f / NT_F)) * tw[o];
    }
    return;
  }

  // XCD-aware bijective swizzle (1536 = 8*192)
  {
    int wid = (blk & 7) * 192 + (blk >> 3);
    blk = wid;
  }

  __shared__ float vsp[RB][288];   // padded cols: idx = col + 16
  __shared__ float gkl[32];
  int rg = blk & (RB - 1);
  int bc = blk >> 4;               // log2(RB) = 4
  int b = bc / CH;
  int y0 = rg * RB;
  const float* xp = x + (size_t)bc * (HH * WW);

  // wave 0 computes this batch's gaussian kernel into LDS
  if (tid < 64) {
    float wexp = 0.0f;
    if (tid < KS) {
      float sigma = sched[t[b]];
      float xg = (float)(tid - PAD) / sigma;
      wexp = expf(-0.5f * xg * xg);
    }
    float s = wexp;
#pragma unroll
    for (int off = 32; off > 0; off >>= 1) s += __shfl_down(s, off);
    float tot = __shfl(s, 0);
    if (tid < 32) gkl[tid] = wexp / tot;
  }
  __syncthreads();

  // gaussian taps into registers once (wave-uniform broadcast reads)
  float gk[KS];
#pragma unroll
  for (int kk = 0; kk < KS; kk++) gk[kk] = gkl[kk];

  // ---- vertical pass, 2 chunks of 8 output rows (no-spill pattern) ----
#pragma unroll
  for (int ch = 0; ch < 2; ch++) {
    float acc[8];
#pragma unroll
    for (int yy = 0; yy < 8; yy++) acc[yy] = 0.0f;
#pragma unroll
    for (int i = 0; i < 36; i++) {         // input rows y0+8ch-14 .. +21
      int gy = y0 + 8 * ch - PAD + i;
      gy = (gy < 0) ? -gy : gy;
      gy = (gy >= HH) ? (2 * HH - 2 - gy) : gy;
      float v = xp[gy * WW + tid];
#pragma unroll
      for (int yy = 0; yy < 8; yy++) {
        int kk = i - yy;                   // compile-time per (i,yy)
        if (kk >= 0 && kk < KS) acc[yy] += gk[kk] * v;
      }
    }
#pragma unroll
    for (int yy = 0; yy < 8; yy++) vsp[8 * ch + yy][tid + 16] = acc[yy];
  }
  __syncthreads();
  {
    // 256 threads = 16 rows x 16 cols: single-pass horizontal mirror pads
    int row = tid >> 4, i2 = tid & 15;
    vsp[row][i2] = vsp[row][32 - i2];
    vsp[row][272 + i2] = vsp[row][270 - i2];
  }
  __syncthreads();

  size_t zb = (size_t)bc * (HH * WW);
#pragma unroll
  for (int it = 0; it < RB / 4; ++it) {   // 4 its: 1024 4-px units / 256 thr
    int unit = tid + 256 * it;
    int row = unit >> 6, cg = unit & 63;
    float w[36];
#pragma unroll
    for (int i = 0; i < 9; i++)
      *(float4*)&w[4 * i] = *(const float4*)&vsp[row][4 * (cg + i)];
    float o0 = 0, o1 = 0, o2 = 0, o3 = 0;
#pragma unroll
    for (int kk = 0; kk < KS; kk++) {
      float kv = gk[kk];
      o0 += kv * w[2 + kk];
      o1 += kv * w[3 + kk];
      o2 += kv * w[4 + kk];
      o3 += kv * w[5 + kk];
    }
    unsigned u0 = pk_bf16(o0, o1);
    unsigned u1 = pk_bf16(o2, o3);
    *(uint2*)&z[zb + (size_t)(y0 + row) * WW + 4 * cg] = make_uint2(u0, u1);
  }
}

// ---------------- fused conv1+ReLU+conv2+MSE, 2-tile pipelined ----------------
// grid (8,16,B); block 256 = 4 waves; TWO 16x16 output tiles per block.
// Flow: stage t1 -> B1 -> [issue t2 z-staging loads] -> conv t1 (covers them)
// -> write t2 staging -> B2 -> [issue t2 MSE x loads] -> conv t2 -> reduce.
// bounds(256,2): LDS caps occupancy at 4 blocks/CU anyway; the low declared
// wave target frees the allocator to ~128 regs (peak live ~100) -> no spill.
__global__ __launch_bounds__(256, 2) void convloss_kernel(
    const float* __restrict__ x, const float* __restrict__ ws,
    const float* __restrict__ b2g, float* __restrict__ partial) {
  __shared__ __align__(16) unsigned short zsA[400 * 4];      // tile1 staging
  __shared__ __align__(16) unsigned short zsB[400 * 4];      // tile2 staging
  __shared__ __align__(16) unsigned short hsw[4 * 6 * 18 * 32]; // per-wave strips
  __shared__ float wsum[4];

  const float* tcond = ws + 1024;
  const unsigned short* w1n = (const unsigned short*)(ws + 2048);
  const unsigned short* w2c = (const unsigned short*)(ws + 2816);
  const unsigned short* zg = (const unsigned short*)(ws + 5120);

  // XCD-aware bijective swizzle (4096 = 8*512)
  int flat = (blockIdx.z * 16 + blockIdx.y) * 8 + blockIdx.x;
  int wid = (flat & 7) * 512 + (flat >> 3);
  int b = wid >> 7;
  int by = (wid >> 3) & 15;
  int bxp = wid & 7;

  int tid = threadIdx.x;
  int x0a = bxp * 32, x0b = x0a + 16;
  int y0 = by * 16;
  const unsigned short* zbp = zg + (size_t)b * 3 * HH * WW;

  int lane = tid & 63;
  int q = lane >> 4;        // quad (16x16 shapes)
  int col = lane & 15;      // 16x16 m/n index
  int col32 = lane & 31;    // 32x32 n index (pixel)
  int h = lane >> 5;        // 32x32 half
  int wv = tid >> 6;        // wave id

  int colc = (col < 3) ? col : 0;
  float b2v = b2g[colc];
  const float* xb = x + (size_t)b * 3 * HH * WW;
  const float* xrow = xb + colc * (HH * WW) + (y0 + wv * 4) * WW + q * 4;

  // staging geometry (tid<200): 2-px units
  int zy = tid / 10;
  int zx2 = tid - zy * 10;

  auto stage_load = [&](int x0t, unsigned& c0, unsigned& c1, unsigned& c2) {
    int gy = y0 - 2 + zy;
    int gx0 = x0t - 2 + 2 * zx2;
    bool ok = ((unsigned)gy < (unsigned)HH) && ((unsigned)gx0 < (unsigned)(WW - 1));
    int cy = (gy < 0) ? 0 : ((gy > 255) ? 255 : gy);
    int cx = (gx0 < 0) ? 0 : ((gx0 > 254) ? 254 : gx0);
    int gi = cy * WW + cx;
    c0 = *(const unsigned*)&zbp[gi];
    c1 = *(const unsigned*)&zbp[HH * WW + gi];
    c2 = *(const unsigned*)&zbp[2 * HH * WW + gi];
    unsigned m = ok ? 0xFFFFFFFFu : 0u;
    c0 &= m; c1 &= m; c2 &= m;
  };
  auto stage_write = [&](unsigned c0, unsigned c1, unsigned c2, unsigned short* zs) {
    uint4 o;
    o.x = (c0 & 0xFFFFu) | (c1 << 16);        // px0: ci0,ci1
    o.y = c2 & 0xFFFFu;                       // px0: ci2,pad
    o.z = (c0 >> 16) | (c1 & 0xFFFF0000u);    // px1: ci0,ci1
    o.w = c2 >> 16;                           // px1: ci2,pad
    *(uint4*)&zs[(zy * 20 + 2 * zx2) * 4] = o;
  };

  // ---- stage tile1 ----
  if (tid < 200) {
    unsigned c0, c1, c2;
    stage_load(x0a, c0, c1, c2);
    stage_write(c0, c1, c2, zsA);
  }

  // conv1 A fragments = weights [m=och][k=slot(h*8+j)]: b128 each
  U4 W0, W1f, W2f;
  W0.u4  = *(const uint4*)(w1n + 0 * 512 + col32 * 16 + h * 8);
  W1f.u4 = *(const uint4*)(w1n + 1 * 512 + col32 * 16 + h * 8);
  W2f.u4 = *(const uint4*)(w1n + 2 * 512 + col32 * 16 + h * 8);

  // conv1 C-init: tcond bias per (reg,h)
  f32x16 tc16;
#pragma unroll
  for (int r1 = 0; r1 < 4; r1++) {
    float4 v = *(const float4*)(tcond + b * 32 + 4 * h + 8 * r1);
    tc16[4 * r1 + 0] = v.x;
    tc16[4 * r1 + 1] = v.y;
    tc16[4 * r1 + 2] = v.z;
    tc16[4 * r1 + 3] = v.w;
  }

  // MSE x values for tile1 (cold HBM; consumed at end of conv t1) — SCALARS
  float4 xa0 = *(const float4*)&xrow[x0a];
  float4 xa1 = *(const float4*)&xrow[x0a + WW];
  float4 xa2 = *(const float4*)&xrow[x0a + 2 * WW];
  float4 xa3 = *(const float4*)&xrow[x0a + 3 * WW];

  __syncthreads();   // B1: zsA staged

  // ---- issue tile2's z-staging loads NOW: ~900cy HBM/L2 latency hides
  // under conv t1 (~1500+cy); consumed at stage_write before B2.
  unsigned s0b = 0, s1b = 0, s2b = 0;
  if (tid < 200) stage_load(x0b, s0b, s1b, s2b);

  // per-lane b64 read offsets (ushort units) for the 3 conv1 MFMAs' tap pairs
  int oA0 = h ? 8 : 0, oB0 = h ? 80 : 4;
  int oA1 = h ? 160 : 84, oB1 = h ? 164 : 88;
  const int oA2 = 168;
  char* hbw = (char*)hsw + wv * 6912;

  // ---- one full tile; MSE x comes in BY VALUE (stays in VGPRs) ----
  auto conv_tile = [&](const unsigned short* zs, float4 xv0, float4 xv1,
                       float4 xv2, float4 xv3) -> float {
#pragma unroll
    for (int g2 = 0; g2 < 4; g2++) {
      int e = g2 * 32 + col32;
      int ec = (e > 107) ? 107 : e;
      int row_l = ec / 18;              // 0..5
      int px = ec - row_l * 18;         // 0..17
      int ub = ((4 * wv + row_l) * 20 + px) * 4;
      uint2 l0 = *(const uint2*)&zs[ub + oA0];
      uint2 l1 = *(const uint2*)&zs[ub + oB0];
      uint2 l2 = *(const uint2*)&zs[ub + oA1];
      uint2 l3 = *(const uint2*)&zs[ub + oB1];
      uint2 l4 = *(const uint2*)&zs[ub + oA2];
      U4 Bz0, Bz1, Bz2;
      Bz0.u4 = make_uint4(l0.x, l0.y, l1.x, l1.y);
      Bz1.u4 = make_uint4(l2.x, l2.y, l3.x, l3.y);
      Bz2.u4 = make_uint4(l4.x, l4.y, 0u, 0u);
      f32x16 a = __builtin_amdgcn_mfma_f32_32x32x16_bf16(W0.s8, Bz0.s8, tc16, 0, 0, 0);
      a = __builtin_amdgcn_mfma_f32_32x32x16_bf16(W1f.s8, Bz1.s8, a, 0, 0, 0);
      a = __builtin_amdgcn_mfma_f32_32x32x16_bf16(W2f.s8, Bz2.s8, a, 0, 0, 0);
      if (e < 108) {
        unsigned wpk[8];
#pragma unroll
        for (int m = 0; m < 8; m++)
          wpk[m] = pk_bf16(fmaxf(a[2 * m], 0.0f), fmaxf(a[2 * m + 1], 0.0f));
        int wb = row_l * 1152 + px * 64 + ((32 * h) ^ ((px & 2) << 4));
        *(uint4*)(hbw + wb)      = make_uint4(wpk[0], wpk[1], wpk[2], wpk[3]);
        *(uint4*)(hbw + wb + 16) = make_uint4(wpk[4], wpk[5], wpk[6], wpk[7]);
      }
    }
    // NO barrier: conv2 reads only this wave's strip (same-wave, in-order LDS)

    // conv2 B-frags loaded per tile (L2-hot; keeps conv1 reg pressure low)
    U4 Bt[3][3];
    {
      const unsigned short* wbase = w2c + col * 32 + q * 8;
#pragma unroll
      for (int dy = 0; dy < 3; dy++)
#pragma unroll
        for (int dx = 0; dx < 3; dx++)
          Bt[dy][dx].u4 = *(const uint4*)(wbase + (dy * 3 + dx) * 512);
    }

    const f32x4 bcv = {b2v, b2v, b2v, b2v};
    f32x4 dacc[4];
#pragma unroll
    for (int i = 0; i < 4; i++) dacc[i] = bcv;
#pragma unroll
    for (int dx = 0; dx < 3; dx++) {
      int px = col + dx;                         // 0..17
      const char* bp = (const char*)hbw + px * 64 + ((q * 16) ^ ((px & 2) << 4));
#pragma unroll
      for (int rr = 0; rr < 6; rr++) {
        U4 A;
        A.u4 = *(const uint4*)(bp + rr * 1152);  // one b128, imm offset
        if (rr < 4)
          dacc[rr] = __builtin_amdgcn_mfma_f32_16x16x32_bf16(A.s8, Bt[0][dx].s8, dacc[rr], 0, 0, 0);
        if (rr >= 1 && rr < 5)
          dacc[rr - 1] = __builtin_amdgcn_mfma_f32_16x16x32_bf16(A.s8, Bt[1][dx].s8, dacc[rr - 1], 0, 0, 0);
        if (rr >= 2)
          dacc[rr - 2] = __builtin_amdgcn_mfma_f32_16x16x32_bf16(A.s8, Bt[2][dx].s8, dacc[rr - 2], 0, 0, 0);
      }
    }

    float s = 0.0f;
    if (col < 3) {
      float d;
      d = xv0.x - dacc[0][0]; s += d * d;
      d = xv0.y - dacc[0][1]; s += d * d;
      d = xv0.z - dacc[0][2]; s += d * d;
      d = xv0.w - dacc[0][3]; s += d * d;
      d = xv1.x - dacc[1][0]; s += d * d;
      d = xv1.y - dacc[1][1]; s += d * d;
      d = xv1.z - dacc[1][2]; s += d * d;
      d = xv1.w - dacc[1][3]; s += d * d;
      d = xv2.x - dacc[2][0]; s += d * d;
      d = xv2.y - dacc[2][1]; s += d * d;
      d = xv2.z - dacc[2][2]; s += d * d;
      d = xv2.w - dacc[2][3]; s += d * d;
      d = xv3.x - dacc[3][0]; s += d * d;
      d = xv3.y - dacc[3][1]; s += d * d;
      d = xv3.z - dacc[3][2]; s += d * d;
      d = xv3.w - dacc[3][3]; s += d * d;
    }
    return s;
  };

  // ---- tile1 compute (t2 z-staging loads in flight underneath) ----
  float sacc = conv_tile(zsA, xa0, xa1, xa2, xa3);

  // ---- write tile2 staging (vmcnt wait was hidden under conv t1) ----
  if (tid < 200) stage_write(s0b, s1b, s2b, zsB);
  __syncthreads();   // B2: zsB staged; hsw t1 reads done (same-wave order)

  // ---- issue tile2 MSE x loads AFTER B2: covered by conv t2 (~1500cy),
  // no intervening barrier before their consumption.
  float4 xb0 = *(const float4*)&xrow[x0b];
  float4 xb1 = *(const float4*)&xrow[x0b + WW];
  float4 xb2 = *(const float4*)&xrow[x0b + 2 * WW];
  float4 xb3 = *(const float4*)&xrow[x0b + 3 * WW];

  // ---- tile2 compute ----
  sacc += conv_tile(zsB, xb0, xb1, xb2, xb3);

  // ---- block reduce ----
#pragma unroll
  for (int off = 32; off > 0; off >>= 1) sacc += __shfl_down(sacc, off);
  if (lane == 0) wsum[wv] = sacc;
  __syncthreads();   // B3
  if (tid == 0) {
    int bid = (b * 16 + by) * 8 + bxp;
    partial[bid] = wsum[0] + wsum[1] + wsum[2] + wsum[3];
  }
}

// ---------------- final reduce: 4096 partials -> out[0] ----------------
__global__ __launch_bounds__(256) void reduce_kernel(const float* __restrict__ partial,
                                                     float* __restrict__ out) {
  __shared__ float wsum[4];
  int tid = threadIdx.x;
  float s = 0.0f;
#pragma unroll
  for (int i = 0; i < 4; i++) {
    float4 v = *(const float4*)&partial[(tid + 256 * i) * 4];
    s += v.x + v.y + v.z + v.w;
  }
#pragma unroll
  for (int off = 32; off > 0; off >>= 1) s += __shfl_down(s, off);
  if ((tid & 63) == 0) wsum[tid >> 6] = s;
  __syncthreads();
  if (tid == 0)
    out[0] = (wsum[0] + wsum[1] + wsum[2] + wsum[3]) * (1.0f / 6291456.0f);
}

extern "C" void kernel_launch(void* const* d_in, const int* in_sizes, int n_in,
                              void* d_out, int out_size, void* d_ws, size_t ws_size,
                              hipStream_t stream) {
  const float* x = (const float*)d_in[0];
  const int* t = (const int*)d_in[1];
  const float* W1 = (const float*)d_in[2];
  const float* b1 = (const float*)d_in[3];
  const float* tw = (const float*)d_in[4];
  const float* W2 = (const float*)d_in[5];
  const float* b2 = (const float*)d_in[6];
  const float* sched = (const float*)d_in[7];
  float* out = (float*)d_out;
  float* ws = (float*)d_ws;
  unsigned short* z = (unsigned short*)(ws + 5120);
  float* partial = ws + PARTIAL_OFF;

  blur_kernel<<<BATCH * CH * RB + 1, 256, 0, stream>>>(x, t, sched, W1, b1, tw, W2, ws, z);
  dim3 grid(8, 16, BATCH);
  convloss_kernel<<<grid, 256, 0, stream>>>(x, ws, b2, partial);
  reduce_kernel<<<1, 256, 0, stream>>>(partial, out);
}

// Round 17
// 134.927 us; speedup vs baseline: 1.1305x; 1.0580x over previous
//
#include <hip/hip_runtime.h>
#include <hip/hip_bf16.h>

#define BATCH 32
#define CH 3
#define HH 256
#define WW 256
#define KS 29
#define PAD 14
#define NT_F 1000.0f

// blur band height: 16 rows -> 1536 blocks; with bounds(256,4) the reg cap is
// 128 (no spill at ~80 live) and occupancy = 4 blocks/CU. [R11 best config]
#define RB 16

typedef __attribute__((ext_vector_type(8))) short short8;
typedef __attribute__((ext_vector_type(4))) float f32x4;
typedef __attribute__((ext_vector_type(16))) float f32x16;

union U4 { short8 s8; uint4 u4; };

__device__ inline unsigned short bf16rne(float f) {
  unsigned u = __float_as_uint(f);
  unsigned r = (u + 0x7FFFu + ((u >> 16) & 1u)) >> 16;
  return (unsigned short)r;
}
__device__ inline unsigned pk_bf16(float a, float b) {
  union { __hip_bfloat162 h2; unsigned u; } cv;
  cv.h2 = __float22bfloat162_rn(make_float2(a, b));
  return cv.u;
}

// ws float layout:
//   (unused)  [1024]          @ 0
//   tcond [32][32]            @ 1024
//   w1n   ushort[3][32][16]   @ 2048
//   w2c   ushort[9][16][32]   @ 2816  (slot s holds och perm(s))
//   z     ushort[32][3][256][256] @ 5120  (bf16 blurred)
//   partial float[8192]       @ 3151872
//
// LESSONS LOG (final):
// R1: conv1-write bank fix correct but off critical path.
// R3: XCD swizzle cut convloss FETCH 58.5->18.5MB, dur unchanged.
// R5: private arrays need compile-time indexing (ring mod-6 -> scratch).
// R6: convloss occupancy theory falsified (+13% waves, dur worse).
// R7: barrier-removal neutral. Keep wave-private conv1 variant.
// R8: chunked no-spill blur ~43us. R9: fusion refuted (3.75x redundancy).
// R10: launch-bounds spill rule: declared waves cap VGPR (pool ~512/SIMD).
// R11: bounds(256,4)+RB16: total 134.06 (BEST). blur at per-block floor.
// R13/R15: 2-tile pipeline scratch bugs (lambda ptr-arg; allocator band).
// R16: 2-tile pipeline CLEAN (VGPR 76, scratch 16KB) and still 53.5 vs 44:
//     FALSIFIED. 4096 blocks x 2 sequential tiles < 8192 parallel tiles
//     (occupancy 29% vs 42%) — independent parallel work beats in-block
//     pipelining here. REVERTED to R11-exact (this file).
// Floor ledger: fill ~44.5 (harness re-poison, 268MB @ 75% HBM peak,
//     untouchable) + blur ~42 + convloss ~44 + reduce ~3 = ~134. All
//     actionable theories for blur/convloss measured and falsified.
//
// NOTE (r14): do NOT fold reduce into convloss via threadfence+atomic --
// device-scope fence across 8 non-coherent XCD L2s = 6x regression.

#define PARTIAL_OFF 3151872

// ---------------- blur (+ embedded weight-prep in last block) ----------------
__global__ __launch_bounds__(256, 4) void blur_kernel(
    const float* __restrict__ x, const int* __restrict__ t,
    const float* __restrict__ sched, const float* __restrict__ W1,
    const float* __restrict__ b1, const float* __restrict__ tw,
    const float* __restrict__ W2, float* __restrict__ ws,
    unsigned short* __restrict__ z) {
  int blk = blockIdx.x;
  int tid = threadIdx.x;

  if (blk >= BATCH * CH * RB) {
    // ---- weight-prep block (runs once; convloss launches after this kernel)
    float* tcond = ws + 1024;
    unsigned short* w1n = (unsigned short*)(ws + 2048);
    unsigned short* w2c = (unsigned short*)(ws + 2816);
    for (int i = tid; i < 1536; i += 256) {          // w1n [mf][och][slot]
      int mf = i >> 9, r = i & 511;
      int och = r >> 4, s = r & 15;
      int tp = mf * 4 + (s >> 2), ci = s & 3;
      w1n[i] = (ci < 3 && tp < 9) ? bf16rne(W1[och * 27 + ci * 9 + tp])
                                  : (unsigned short)0;
    }
    for (int i = tid; i < 4608; i += 256) {          // w2c [tap][oc][slot(perm)]
      int tap = i >> 9, r = i & 511;
      int n = r >> 5, s = r & 31;
      int och = (s & 3) + 8 * ((s >> 2) & 3) + 4 * (s >> 4);   // perm(s)
      int dy = tap / 3, dx = tap - dy * 3;
      w2c[i] = (n < 3) ? bf16rne(W2[((n * 32 + och) * 3 + dy) * 3 + dx])
                       : (unsigned short)0;
    }
    for (int i = tid; i < 1024; i += 256) {          // tcond
      int b = i >> 5, o = i & 31;
      tcond[i] = b1[o] + ((float)t[b] * (1.0f / NT_F)) * tw[o];
    }
    return;
  }

  // XCD-aware bijective swizzle (1536 = 8*192)
  {
    int wid = (blk & 7) * 192 + (blk >> 3);
    blk = wid;
  }

  __shared__ float vsp[RB][288];   // padded cols: idx = col + 16
  __shared__ float gkl[32];
  int rg = blk & (RB - 1);
  int bc = blk >> 4;               // log2(RB) = 4
  int b = bc / CH;
  int y0 = rg * RB;
  const float* xp = x + (size_t)bc * (HH * WW);

  // wave 0 computes this batch's gaussian kernel into LDS
  if (tid < 64) {
    float wexp = 0.0f;
    if (tid < KS) {
      float sigma = sched[t[b]];
      float xg = (float)(tid - PAD) / sigma;
      wexp = expf(-0.5f * xg * xg);
    }
    float s = wexp;
#pragma unroll
    for (int off = 32; off > 0; off >>= 1) s += __shfl_down(s, off);
    float tot = __shfl(s, 0);
    if (tid < 32) gkl[tid] = wexp / tot;
  }
  __syncthreads();

  // gaussian taps into registers once (wave-uniform broadcast reads)
  float gk[KS];
#pragma unroll
  for (int kk = 0; kk < KS; kk++) gk[kk] = gkl[kk];

  // ---- vertical pass, 2 chunks of 8 output rows (no-spill pattern) ----
#pragma unroll
  for (int ch = 0; ch < 2; ch++) {
    float acc[8];
#pragma unroll
    for (int yy = 0; yy < 8; yy++) acc[yy] = 0.0f;
#pragma unroll
    for (int i = 0; i < 36; i++) {         // input rows y0+8ch-14 .. +21
      int gy = y0 + 8 * ch - PAD + i;
      gy = (gy < 0) ? -gy : gy;
      gy = (gy >= HH) ? (2 * HH - 2 - gy) : gy;
      float v = xp[gy * WW + tid];
#pragma unroll
      for (int yy = 0; yy < 8; yy++) {
        int kk = i - yy;                   // compile-time per (i,yy)
        if (kk >= 0 && kk < KS) acc[yy] += gk[kk] * v;
      }
    }
#pragma unroll
    for (int yy = 0; yy < 8; yy++) vsp[8 * ch + yy][tid + 16] = acc[yy];
  }
  __syncthreads();
  {
    // 256 threads = 16 rows x 16 cols: single-pass horizontal mirror pads
    int row = tid >> 4, i2 = tid & 15;
    vsp[row][i2] = vsp[row][32 - i2];
    vsp[row][272 + i2] = vsp[row][270 - i2];
  }
  __syncthreads();

  size_t zb = (size_t)bc * (HH * WW);
#pragma unroll
  for (int it = 0; it < RB / 4; ++it) {   // 4 its: 1024 4-px units / 256 thr
    int unit = tid + 256 * it;
    int row = unit >> 6, cg = unit & 63;
    float w[36];
#pragma unroll
    for (int i = 0; i < 9; i++)
      *(float4*)&w[4 * i] = *(const float4*)&vsp[row][4 * (cg + i)];
    float o0 = 0, o1 = 0, o2 = 0, o3 = 0;
#pragma unroll
    for (int kk = 0; kk < KS; kk++) {
      float kv = gk[kk];
      o0 += kv * w[2 + kk];
      o1 += kv * w[3 + kk];
      o2 += kv * w[4 + kk];
      o3 += kv * w[5 + kk];
    }
    unsigned u0 = pk_bf16(o0, o1);
    unsigned u1 = pk_bf16(o2, o3);
    *(uint2*)&z[zb + (size_t)(y0 + row) * WW + 4 * cg] = make_uint2(u0, u1);
  }
}

// ---------------- fused conv1+ReLU+conv2+MSE via bf16 MFMA ----------------
// R7-exact (best measured variant): single mid-kernel barrier, wave-private
// conv1 strips, no B2.
__global__ __launch_bounds__(256, 5) void convloss_kernel(
    const float* __restrict__ x, const float* __restrict__ ws,
    const float* __restrict__ b2g, float* __restrict__ partial) {
  __shared__ __align__(16) unsigned short zs4[400 * 4];      // [y*20+x][ci0..2,pad]
  __shared__ __align__(16) unsigned short hsw[4 * 6 * 18 * 32]; // per-wave strips
  __shared__ float wsum[4];

  const float* tcond = ws + 1024;
  const unsigned short* w1n = (const unsigned short*)(ws + 2048);
  const unsigned short* w2c = (const unsigned short*)(ws + 2816);
  const unsigned short* zg = (const unsigned short*)(ws + 5120);

  // XCD-aware bijective swizzle (8192 = 8*1024)
  int flat = (blockIdx.z * 16 + blockIdx.y) * 16 + blockIdx.x;
  int wid = (flat & 7) * 1024 + (flat >> 3);
  int b = wid >> 8;
  int by = (wid >> 4) & 15;
  int bx = wid & 15;

  int tid = threadIdx.x;
  int x0 = bx * 16, y0 = by * 16;
  const unsigned short* zbp = zg + (size_t)b * 3 * HH * WW;

  int lane = tid & 63;
  int q = lane >> 4;        // quad (16x16 shapes)
  int col = lane & 15;      // 16x16 m/n index
  int col32 = lane & 31;    // 32x32 n index (pixel)
  int h = lane >> 5;        // 32x32 half
  int wv = tid >> 6;        // wave id

  // ---- vectorized z staging: 200 threads, 2-px units, b32 loads ----
  if (tid < 200) {
    int zy = tid / 10;
    int zx2 = tid - zy * 10;
    int gy = y0 - 2 + zy;
    int gx0 = x0 - 2 + 2 * zx2;
    bool ok = ((unsigned)gy < (unsigned)HH) && ((unsigned)gx0 < (unsigned)(WW - 1));
    int cy = (gy < 0) ? 0 : ((gy > 255) ? 255 : gy);
    int cx = (gx0 < 0) ? 0 : ((gx0 > 254) ? 254 : gx0);
    int gi = cy * WW + cx;
    unsigned c0 = *(const unsigned*)&zbp[gi];
    unsigned c1 = *(const unsigned*)&zbp[HH * WW + gi];
    unsigned c2 = *(const unsigned*)&zbp[2 * HH * WW + gi];
    unsigned m = ok ? 0xFFFFFFFFu : 0u;
    c0 &= m; c1 &= m; c2 &= m;
    uint4 o;
    o.x = (c0 & 0xFFFFu) | (c1 << 16);        // px0: ci0,ci1
    o.y = c2 & 0xFFFFu;                       // px0: ci2,pad
    o.z = (c0 >> 16) | (c1 & 0xFFFF0000u);    // px1: ci0,ci1
    o.w = c2 >> 16;                           // px1: ci2,pad
    *(uint4*)&zs4[(zy * 20 + 2 * zx2) * 4] = o;
  }

  // conv1 A fragments = weights [m=och][k=slot(h*8+j)]: b128 each
  U4 W0, W1f, W2f;
  W0.u4  = *(const uint4*)(w1n + 0 * 512 + col32 * 16 + h * 8);
  W1f.u4 = *(const uint4*)(w1n + 1 * 512 + col32 * 16 + h * 8);
  W2f.u4 = *(const uint4*)(w1n + 2 * 512 + col32 * 16 + h * 8);

  // conv1 C-init: tcond bias per (reg,h): och = (reg&3) + 8*(reg>>2) + 4h
  f32x16 tc16;
#pragma unroll
  for (int r1 = 0; r1 < 4; r1++) {
    float4 v = *(const float4*)(tcond + b * 32 + 4 * h + 8 * r1);
    tc16[4 * r1 + 0] = v.x;
    tc16[4 * r1 + 1] = v.y;
    tc16[4 * r1 + 2] = v.z;
    tc16[4 * r1 + 3] = v.w;
  }

  int colc = (col < 3) ? col : 0;
  float b2v = b2g[colc];

  // MSE x prefetch HOISTED above B1 (cold HBM stream; consumed at the end)
  const float* xb = x + (size_t)b * 3 * HH * WW;
  float4 xpre[4];
#pragma unroll
  for (int i = 0; i < 4; i++) {
    int g2 = wv * 4 + i;
    xpre[i] = *(const float4*)&xb[colc * (HH * WW) + (y0 + g2) * WW + x0 + q * 4];
  }

  __syncthreads();   // B1: z staged (ONLY mid-kernel barrier)

  // per-lane b64 read offsets (ushort units) for the 3 MFMAs' tap pairs
  int oA0 = h ? 8 : 0, oB0 = h ? 80 : 4;
  int oA1 = h ? 160 : 84, oB1 = h ? 164 : 88;
  const int oA2 = 168;

  // ---- P1: wave-private conv1 -> own h strip (rows 4wv..4wv+5, 18 px) ----
  char* hbw = (char*)hsw + wv * 6912;
#pragma unroll
  for (int g2 = 0; g2 < 4; g2++) {
    int e = g2 * 32 + col32;
    int ec = (e > 107) ? 107 : e;
    int row_l = ec / 18;              // 0..5
    int px = ec - row_l * 18;         // 0..17
    int ub = ((4 * wv + row_l) * 20 + px) * 4;
    uint2 l0 = *(const uint2*)&zs4[ub + oA0];
    uint2 l1 = *(const uint2*)&zs4[ub + oB0];
    uint2 l2 = *(const uint2*)&zs4[ub + oA1];
    uint2 l3 = *(const uint2*)&zs4[ub + oB1];
    uint2 l4 = *(const uint2*)&zs4[ub + oA2];
    U4 Bz0, Bz1, Bz2;
    Bz0.u4 = make_uint4(l0.x, l0.y, l1.x, l1.y);
    Bz1.u4 = make_uint4(l2.x, l2.y, l3.x, l3.y);
    Bz2.u4 = make_uint4(l4.x, l4.y, 0u, 0u);
    f32x16 a = __builtin_amdgcn_mfma_f32_32x32x16_bf16(W0.s8, Bz0.s8, tc16, 0, 0, 0);
    a = __builtin_amdgcn_mfma_f32_32x32x16_bf16(W1f.s8, Bz1.s8, a, 0, 0, 0);
    a = __builtin_amdgcn_mfma_f32_32x32x16_bf16(W2f.s8, Bz2.s8, a, 0, 0, 0);
    if (e < 108) {
      unsigned wpk[8];
#pragma unroll
      for (int m = 0; m < 8; m++)
        wpk[m] = pk_bf16(fmaxf(a[2 * m], 0.0f), fmaxf(a[2 * m + 1], 0.0f));
      int wb = row_l * 1152 + px * 64 + ((32 * h) ^ ((px & 2) << 4));
      *(uint4*)(hbw + wb)      = make_uint4(wpk[0], wpk[1], wpk[2], wpk[3]);
      *(uint4*)(hbw + wb + 16) = make_uint4(wpk[4], wpk[5], wpk[6], wpk[7]);
    }
  }
  // NO barrier: conv2 reads only this wave's strip (same-wave lgkmcnt).

  // hoist all 9 conv2 B-frags
  U4 Bt[3][3];
  {
    const unsigned short* wbase = w2c + col * 32 + q * 8;
#pragma unroll
    for (int dy = 0; dy < 3; dy++)
#pragma unroll
      for (int dx = 0; dx < 3; dx++)
        Bt[dy][dx].u4 = *(const uint4*)(wbase + (dy * 3 + dx) * 512);
  }

  // ---- conv2, loop-rotated: 18 A-reads, 36 accumulating MFMAs ----
  const f32x4 bcv = {b2v, b2v, b2v, b2v};
  f32x4 dacc[4];
#pragma unroll
  for (int i = 0; i < 4; i++) dacc[i] = bcv;
  {
    const char* hb = (const char*)hsw + wv * 6912;
#pragma unroll
    for (int dx = 0; dx < 3; dx++) {
      int px = col + dx;                         // 0..17
      const char* bp = hb + px * 64 + ((q * 16) ^ ((px & 2) << 4));
#pragma unroll
      for (int rr = 0; rr < 6; rr++) {
        U4 A;
        A.u4 = *(const uint4*)(bp + rr * 1152);  // one b128, imm offset
        if (rr < 4)
          dacc[rr] = __builtin_amdgcn_mfma_f32_16x16x32_bf16(A.s8, Bt[0][dx].s8, dacc[rr], 0, 0, 0);
        if (rr >= 1 && rr < 5)
          dacc[rr - 1] = __builtin_amdgcn_mfma_f32_16x16x32_bf16(A.s8, Bt[1][dx].s8, dacc[rr - 1], 0, 0, 0);
        if (rr >= 2)
          dacc[rr - 2] = __builtin_amdgcn_mfma_f32_16x16x32_bf16(A.s8, Bt[2][dx].s8, dacc[rr - 2], 0, 0, 0);
      }
    }
  }

  // ---- MSE partial (oc=col<3, ox=q*4+r, oy=wv*4+i) ----
  float s = 0.0f;
  if (col < 3) {
#pragma unroll
    for (int i = 0; i < 4; i++) {
      float4 xv = xpre[i];
      float d0 = xv.x - dacc[i][0];
      float d1 = xv.y - dacc[i][1];
      float d2 = xv.z - dacc[i][2];
      float d3 = xv.w - dacc[i][3];
      s += d0 * d0 + d1 * d1 + d2 * d2 + d3 * d3;
    }
  }
#pragma unroll
  for (int off = 32; off > 0; off >>= 1) s += __shfl_down(s, off);
  if (lane == 0) wsum[wv] = s;
  __syncthreads();   // B3
  if (tid == 0) {
    int bid = (b * 16 + by) * 16 + bx;
    partial[bid] = wsum[0] + wsum[1] + wsum[2] + wsum[3];
  }
}

// ---------------- final reduce: 8192 partials -> out[0] ----------------
__global__ __launch_bounds__(256) void reduce_kernel(const float* __restrict__ partial,
                                                     float* __restrict__ out) {
  __shared__ float wsum[4];
  int tid = threadIdx.x;
  float s = 0.0f;
#pragma unroll
  for (int i = 0; i < 8; i++) {
    float4 v = *(const float4*)&partial[(tid + 256 * i) * 4];
    s += v.x + v.y + v.z + v.w;
  }
#pragma unroll
  for (int off = 32; off > 0; off >>= 1) s += __shfl_down(s, off);
  if ((tid & 63) == 0) wsum[tid >> 6] = s;
  __syncthreads();
  if (tid == 0)
    out[0] = (wsum[0] + wsum[1] + wsum[2] + wsum[3]) * (1.0f / 6291456.0f);
}

extern "C" void kernel_launch(void* const* d_in, const int* in_sizes, int n_in,
                              void* d_out, int out_size, void* d_ws, size_t ws_size,
                              hipStream_t stream) {
  const float* x = (const float*)d_in[0];
  const int* t = (const int*)d_in[1];
  const float* W1 = (const float*)d_in[2];
  const float* b1 = (const float*)d_in[3];
  const float* tw = (const float*)d_in[4];
  const float* W2 = (const float*)d_in[5];
  const float* b2 = (const float*)d_in[6];
  const float* sched = (const float*)d_in[7];
  float* out = (float*)d_out;
  float* ws = (float*)d_ws;
  unsigned short* z = (unsigned short*)(ws + 5120);
  float* partial = ws + PARTIAL_OFF;

  blur_kernel<<<BATCH * CH * RB + 1, 256, 0, stream>>>(x, t, sched, W1, b1, tw, W2, ws, z);
  dim3 grid(16, 16, BATCH);
  convloss_kernel<<<grid, 256, 0, stream>>>(x, ws, b2, partial);
  reduce_kernel<<<1, 256, 0, stream>>>(partial, out);
}